// Round 13
// baseline (199.590 us; speedup 1.0000x reference)
//
#include <hip/hip_runtime.h>
#include <hip/hip_bf16.h>

#define D_MODEL 1024
#define NUM_HEADS 16
#define D_HEAD 64
#define BATCH 2
#define SEQ 2048
#define TOKENS (BATCH * SEQ) /* 4096 */

typedef __attribute__((ext_vector_type(8))) short bf16x8;
typedef __attribute__((ext_vector_type(4))) float f32x4;
typedef __attribute__((ext_vector_type(2))) unsigned int uint2v;

typedef __attribute__((address_space(1))) const unsigned int as1_uint;
typedef __attribute__((address_space(3))) unsigned int as3_uint;

#define LOG2E 1.44269504088896340736f

// round-to-nearest-even fp32 -> bf16 (bit pattern)
static __device__ __forceinline__ unsigned short f2bf(float f) {
    unsigned int u = __builtin_bit_cast(unsigned int, f);
    u += 0x7fffu + ((u >> 16) & 1u);
    return (unsigned short)(u >> 16);
}

// packed fp32x2 -> bf16x2 (lowers to v_cvt_pk_bf16_f32 on gfx950)
static __device__ __forceinline__ unsigned int pk2bf(float a, float b) {
    __hip_bfloat162 h = __float22bfloat162_rn(float2{a, b});
    unsigned int u;
    __builtin_memcpy(&u, &h, 4);
    return u;
}

// native v_exp_f32 (2^x)
static __device__ __forceinline__ float fast_exp2(float x) {
    return __builtin_amdgcn_exp2f(x);
}

// ---------------------------------------------------------------------------
// R25 (kept): weights-only fp32 -> bf16 conversion.
// ---------------------------------------------------------------------------
__global__ __launch_bounds__(256) void convert_w(
    const float* __restrict__ Wq, const float* __restrict__ Wk,
    const float* __restrict__ Wv, const float* __restrict__ Wp,
    unsigned short* __restrict__ Wqb, unsigned short* __restrict__ Wkb,
    unsigned short* __restrict__ Wvb, unsigned short* __restrict__ Wpb)
{
    int v = blockIdx.x * 256 + threadIdx.x;
    int w = v >> 18;
    int off = v & ((1 << 18) - 1);
    const float* s = (w == 0) ? Wq : (w == 1) ? Wk : (w == 2) ? Wv : Wp;
    unsigned short* d = (w == 0) ? Wqb : (w == 1) ? Wkb : (w == 2) ? Wvb : Wpb;
    float4 f = ((const float4*)s)[off];
    ushort4 o = { f2bf(f.x), f2bf(f.y), f2bf(f.z), f2bf(f.w) };
    ((ushort4*)d)[off] = o;
}

// ---------------------------------------------------------------------------
// R25 (kept): FUSED QKV projection reading x DIRECTLY as fp32. A-staging is
// T14 async-split: issue 2x float4 global loads at iter top, cvt + ds_write
// into buf^1 AFTER compute. Weights via async global_load_lds (preconverted).
// BN=64, 2 blocks/CU, dbuf one-sync.
// ---------------------------------------------------------------------------
__global__ __launch_bounds__(512, 4) void qkv_gemm(
    const float* __restrict__ x,
    const unsigned short* __restrict__ Wqb, const unsigned short* __restrict__ Wkb,
    const unsigned short* __restrict__ Wvb,
    unsigned short* __restrict__ Q, unsigned short* __restrict__ Kb,
    unsigned short* __restrict__ Vt)
{
    const int m0 = blockIdx.x * 128;
    const int n0 = blockIdx.y * 64;

    __shared__ __attribute__((aligned(16))) unsigned short sm[40960]; // 80 KB

    const int t = threadIdx.x;
    const int wave = t >> 6, lane = t & 63;
    const int wm = (wave & 1) * 64, wn = (wave >> 1) * 16;
    const int l15 = lane & 15, quad = lane >> 4;
    const int sw = l15 & 7;

    const unsigned short* Wz[3] = { Wqb, Wkb, Wvb };

    f32x4 acc[3][4];
#pragma unroll
    for (int z = 0; z < 3; z++)
#pragma unroll
        for (int i = 0; i < 4; i++) acc[z][i] = (f32x4)0.f;

    // weights: 512 16B chunks each (1/thread), async DMA
    auto stageW = [&](int k0, int buf) {
        int row = t >> 3, cp = t & 7;
        int c = cp ^ (row & 7);
        int fbase = wave * 64;
#pragma unroll
        for (int z = 0; z < 3; z++)
            __builtin_amdgcn_global_load_lds(
                (as1_uint*)&Wz[z][(size_t)(n0 + row) * D_MODEL + k0 + c * 8],
                (as3_uint*)&sm[buf * 20480 + 8192 + z * 4096 + fbase * 8],
                16, 0, 0);
    };

    // A: 1024 bf16-chunks (2/thread); fp32 source, same XOR-swizzled image
    float4 ar[2][2];
    auto loadA = [&](int k0) {
#pragma unroll
        for (int i = 0; i < 2; i++) {
            int f = wave * 64 + i * 512 + lane;
            int row = f >> 3, cp = f & 7;
            int c = cp ^ (row & 7);
            const float4* p = (const float4*)&x[(size_t)(m0 + row) * D_MODEL + k0 + c * 8];
            ar[i][0] = p[0];
            ar[i][1] = p[1];
        }
    };
    auto writeA = [&](int buf) {
#pragma unroll
        for (int i = 0; i < 2; i++) {
            int f = wave * 64 + i * 512 + lane;
            union { unsigned short s[8]; uint4 v; } u;
            u.s[0] = f2bf(ar[i][0].x); u.s[1] = f2bf(ar[i][0].y);
            u.s[2] = f2bf(ar[i][0].z); u.s[3] = f2bf(ar[i][0].w);
            u.s[4] = f2bf(ar[i][1].x); u.s[5] = f2bf(ar[i][1].y);
            u.s[6] = f2bf(ar[i][1].z); u.s[7] = f2bf(ar[i][1].w);
            *(uint4*)&sm[buf * 20480 + f * 8] = u.v;
        }
    };

    loadA(0);
    stageW(0, 0);
    writeA(0);
    __syncthreads();

    int cur = 0;
    for (int k0 = 0; k0 < D_MODEL; k0 += 64) {
        bool more = (k0 + 64 < D_MODEL);
        if (more) { stageW(k0 + 64, cur ^ 1); loadA(k0 + 64); }

        const unsigned short* lA = &sm[cur * 20480];
#pragma unroll
        for (int kk = 0; kk < 2; kk++) {
            const int cc = ((kk * 4 + quad) ^ sw) * 8;
            bf16x8 a[4];
#pragma unroll
            for (int mt = 0; mt < 4; mt++)
                a[mt] = *(const bf16x8*)&lA[(wm + mt * 16 + l15) * 64 + cc];
#pragma unroll
            for (int z = 0; z < 3; z++) {
                const unsigned short* lB = &sm[cur * 20480 + 8192 + z * 4096];
                bf16x8 b = *(const bf16x8*)&lB[(wn + l15) * 64 + cc];
#pragma unroll
                for (int mt = 0; mt < 4; mt++)
                    acc[z][mt] = __builtin_amdgcn_mfma_f32_16x16x32_bf16(
                        a[mt], b, acc[z][mt], 0, 0, 0);
            }
        }
        if (more) writeA(cur ^ 1);   // cvt + LDS write AFTER compute (T14)
        __syncthreads();             // drains W DMA + orders A writes
        cur ^= 1;
    }

    // ---- epilogue: Q (scaled by log2e), K, Vt ([b][h][dh][s])
#pragma unroll
    for (int mt = 0; mt < 4; mt++)
#pragma unroll
        for (int r = 0; r < 4; r++) {
            int row = m0 + wm + mt * 16 + quad * 4 + r;
            int col = n0 + wn + l15;
            Q[(size_t)row * D_MODEL + col]  = f2bf(acc[0][mt][r] * LOG2E);
            Kb[(size_t)row * D_MODEL + col] = f2bf(acc[1][mt][r]);
        }
    {
        const int b = m0 >> 11;
        const int srow = (m0 & 2047) + wm + quad * 4;
        const int h = n0 >> 6;
        const int dh = wn + l15;
#pragma unroll
        for (int mt = 0; mt < 4; mt++) {
            ushort4 pk = { f2bf(acc[2][mt][0]), f2bf(acc[2][mt][1]),
                           f2bf(acc[2][mt][2]), f2bf(acc[2][mt][3]) };
            *(ushort4*)&Vt[(size_t)((b * 16 + h) * 64 + dh) * SEQ + srow + mt * 16] = pk;
        }
    }
}

// ---------------------------------------------------------------------------
// Flash attention R27: NO s-split -- 4-wave/256-thread blocks, each wave
// owns 32 q-rows and iterates the FULL SEQ (32 iters). Per-buf tile K 8KB +
// V 8KB -> dbuf 32 KB LDS -> 5 blocks/CU = 20 waves/CU (was 2 blocks/16
// waves): 5 independent barrier groups overlap each other's vmcnt drains
// (the session's most-proven lever: R21 +10us, R9 +5us). Cross-shard sO/sL
// reduction epilogue eliminated (each wave normalizes its own rows).
// bh-major grid kept (XCD=bh%8 L2 locality, R10). Staging via
// global_load_lds (pre-swizzled source, linear dest), dbuf, one barrier
// per iter, zero staging VGPRs (R9). P in-register via cvt_pk +
// permlane{32,16}_swap (R2, 0 conflicts).
// LDS (shorts): K[buf] @ buf*8192, V[buf] @ 4096 + buf*8192.
// ---------------------------------------------------------------------------
__global__ __launch_bounds__(256, 5) void attn(
    const unsigned short* __restrict__ Q, const unsigned short* __restrict__ K,
    const unsigned short* __restrict__ Vt, unsigned short* __restrict__ O)
{
    const int q0 = blockIdx.y * 128;
    const int bh = blockIdx.x;
    const int b = bh >> 4, h = bh & 15;
    const size_t base = (size_t)b * SEQ * D_MODEL + (size_t)h * D_HEAD;
    const size_t baseV = (size_t)bh * D_HEAD * SEQ;

    __shared__ __attribute__((aligned(16))) char smem[32768];
    unsigned short* lds = (unsigned short*)smem;

    const int t = threadIdx.x;            // 0..255
    const int wave = t >> 6, lane = t & 63;
    const int l15 = lane & 15, quad = lane >> 4;
    const int qw = q0 + wave * 32;

    bf16x8 ones;
#pragma unroll
    for (int i = 0; i < 8; i++) ones[i] = (short)0x3F80;

    bf16x8 bq[2][2];
#pragma unroll
    for (int mq = 0; mq < 2; mq++)
#pragma unroll
        for (int kk = 0; kk < 2; kk++)
            bq[mq][kk] = *(const bf16x8*)&Q[base +
                (size_t)(qw + mq * 16 + l15) * D_MODEL + kk * 32 + quad * 8];

    const int sw = l15 & 7;

    // async staging: 512 K-chunks + 512 V-chunks per buf per iter,
    // 2+2 per thread; linear LDS dest, XOR swizzle on the GLOBAL source.
    auto stage = [&](int soff, int buf) {
#pragma unroll
        for (int i = 0; i < 2; i++) {
            int f = t + i * 256;
            int row = f >> 3;
            int c = (f & 7) ^ (row & 7);
            __builtin_amdgcn_global_load_lds(
                (as1_uint*)&K[base + (size_t)(soff + row) * D_MODEL + c * 8],
                (as3_uint*)&lds[buf * 8192 + f * 8], 16, 0, 0);
            __builtin_amdgcn_global_load_lds(
                (as1_uint*)&Vt[baseV + (size_t)row * SEQ + soff + c * 8],
                (as3_uint*)&lds[4096 + buf * 8192 + f * 8], 16, 0, 0);
        }
    };

    f32x4 o_acc[2][4];
#pragma unroll
    for (int i = 0; i < 2; i++)
#pragma unroll
        for (int j = 0; j < 4; j++) o_acc[i][j] = (f32x4)0.f;
    f32x4 o_l[2];
#pragma unroll
    for (int i = 0; i < 2; i++) o_l[i] = (f32x4)0.f;

    stage(0, 0);
    __syncthreads();

    int cur = 0;
    for (int s0 = 0; s0 < SEQ; s0 += 64) {
        if (s0 + 64 < SEQ) stage(s0 + 64, cur ^ 1);

        const unsigned short* lK  = lds + cur * 8192;
        const unsigned short* lVt = lds + 4096 + cur * 8192;

        f32x4 st[4][2];
#pragma unroll
        for (int mt = 0; mt < 4; mt++)
#pragma unroll
            for (int mq = 0; mq < 2; mq++) st[mt][mq] = (f32x4)0.f;
#pragma unroll
        for (int kk = 0; kk < 2; kk++) {
            const int cc = ((kk * 4 + quad) ^ sw) * 8;
#pragma unroll
            for (int mt = 0; mt < 4; mt++) {
                bf16x8 ak = *(const bf16x8*)&lK[(mt * 16 + l15) * 64 + cc];
#pragma unroll
                for (int mq = 0; mq < 2; mq++)
                    st[mt][mq] = __builtin_amdgcn_mfma_f32_16x16x32_bf16(
                        ak, bq[mq][kk], st[mt][mq], 0, 0, 0);
            }
        }

#pragma unroll
        for (int mq = 0; mq < 2; mq++)
#pragma unroll
            for (int mt = 0; mt < 4; mt++)
#pragma unroll
                for (int r = 0; r < 4; r++)
                    st[mt][mq][r] = fast_exp2(st[mt][mq][r]);

        // P in-register: cvt_pk + permlane swaps -> PV A-fragments
        bf16x8 pa[2][2];
#pragma unroll
        for (int mq = 0; mq < 2; mq++)
#pragma unroll
            for (int kk = 0; kk < 2; kk++) {
                unsigned int cw[4];
#pragma unroll
                for (int j = 0; j < 2; j++) {
                    unsigned int w0 = pk2bf(st[2 * kk][mq][2 * j],
                                            st[2 * kk][mq][2 * j + 1]);
                    unsigned int w1 = pk2bf(st[2 * kk + 1][mq][2 * j],
                                            st[2 * kk + 1][mq][2 * j + 1]);
                    uint2v uv = __builtin_amdgcn_permlane32_swap(w0, w1, false, false);
                    uint2v f  = __builtin_amdgcn_permlane16_swap(uv[0], uv[1], false, false);
                    cw[j]     = f[0];
                    cw[2 + j] = f[1];
                }
                union { unsigned int w[4]; bf16x8 v; } uu;
                uu.w[0] = cw[0]; uu.w[1] = cw[1]; uu.w[2] = cw[2]; uu.w[3] = cw[3];
                pa[mq][kk] = uu.v;
            }

#pragma unroll
        for (int kk = 0; kk < 2; kk++) {
            const int cc = ((kk * 4 + quad) ^ sw) * 8;
            bf16x8 bv[4];
#pragma unroll
            for (int nt = 0; nt < 4; nt++)
                bv[nt] = *(const bf16x8*)&lVt[(nt * 16 + l15) * 64 + cc];
#pragma unroll
            for (int mq = 0; mq < 2; mq++) {
#pragma unroll
                for (int nt = 0; nt < 4; nt++)
                    o_acc[mq][nt] = __builtin_amdgcn_mfma_f32_16x16x32_bf16(
                        pa[mq][kk], bv[nt], o_acc[mq][nt], 0, 0, 0);
                o_l[mq] = __builtin_amdgcn_mfma_f32_16x16x32_bf16(
                    pa[mq][kk], ones, o_l[mq], 0, 0, 0);
            }
        }
        __syncthreads();   // drains vmcnt: next tile landed; cur free
        cur ^= 1;
    }

    // ---- epilogue: each wave owns its 32 q-rows fully -- normalize+write
#pragma unroll
    for (int mq = 0; mq < 2; mq++) {
        float inv[4];
#pragma unroll
        for (int r = 0; r < 4; r++)
            inv[r] = 1.f / o_l[mq][r];
#pragma unroll
        for (int nt = 0; nt < 4; nt++)
#pragma unroll
            for (int r = 0; r < 4; r++) {
                int row = qw + mq * 16 + quad * 4 + r;
                O[base + (size_t)row * D_MODEL + nt * 16 + l15] =
                    f2bf(o_acc[mq][nt][r] * inv[r]);
            }
    }
}

// ---------------------------------------------------------------------------
// R21 (proven): Output projection, BN=64 + dbuf one-sync, 2 blocks/CU.
// ---------------------------------------------------------------------------
__global__ __launch_bounds__(512, 4) void proj_gemm(
    const unsigned short* __restrict__ A, const unsigned short* __restrict__ W,
    const float* __restrict__ bias, float* __restrict__ out)
{
    const int m0 = blockIdx.x * 128;
    const int n0 = blockIdx.y * 64;

    __shared__ __attribute__((aligned(16))) unsigned short sm[24576]; // 48 KB

    const int t = threadIdx.x;
    const int wave = t >> 6, lane = t & 63;
    const int wm = (wave & 1) * 64, wn = (wave >> 1) * 16;
    const int l15 = lane & 15, quad = lane >> 4;
    const int sw = l15 & 7;

    f32x4 acc[4];
#pragma unroll
    for (int i = 0; i < 4; i++) acc[i] = (f32x4)0.f;

    auto stage = [&](int k0, int buf) {
#pragma unroll
        for (int i = 0; i < 2; i++) {
            int fbase = wave * 64 + i * 512;
            int f = fbase + lane;
            int row = f >> 3, cp = f & 7;
            int c = cp ^ (row & 7);
            __builtin_amdgcn_global_load_lds(
                (as1_uint*)&A[(size_t)(m0 + row) * D_MODEL + k0 + c * 8],
                (as3_uint*)&sm[buf * 12288 + fbase * 8], 16, 0, 0);
        }
        {
            int row = t >> 3, cp = t & 7;
            int c = cp ^ (row & 7);
            int fbase = wave * 64;
            __builtin_amdgcn_global_load_lds(
                (as1_uint*)&W[(size_t)(n0 + row) * D_MODEL + k0 + c * 8],
                (as3_uint*)&sm[buf * 12288 + 8192 + fbase * 8], 16, 0, 0);
        }
    };

    stage(0, 0);
    __syncthreads();

    int cur = 0;
    for (int k0 = 0; k0 < D_MODEL; k0 += 64) {
        if (k0 + 64 < D_MODEL) stage(k0 + 64, cur ^ 1);

        const unsigned short* lA = &sm[cur * 12288];
        const unsigned short* lB = &sm[cur * 12288 + 8192];
#pragma unroll
        for (int kk = 0; kk < 2; kk++) {
            const int cc = ((kk * 4 + quad) ^ sw) * 8;
            bf16x8 a[4];
#pragma unroll
            for (int mt = 0; mt < 4; mt++)
                a[mt] = *(const bf16x8*)&lA[(wm + mt * 16 + l15) * 64 + cc];
            bf16x8 b = *(const bf16x8*)&lB[(wn + l15) * 64 + cc];
#pragma unroll
            for (int mt = 0; mt < 4; mt++)
                acc[mt] = __builtin_amdgcn_mfma_f32_16x16x32_bf16(
                    a[mt], b, acc[mt], 0, 0, 0);
        }
        __syncthreads();
        cur ^= 1;
    }

    const int col = n0 + wn + l15;
    const float bc = bias[col];
#pragma unroll
    for (int mt = 0; mt < 4; mt++)
#pragma unroll
        for (int r = 0; r < 4; r++) {
            int row = m0 + wm + mt * 16 + quad * 4 + r;
            out[(size_t)row * D_MODEL + col] = acc[mt][r] + bc;
        }
}

extern "C" void kernel_launch(void* const* d_in, const int* in_sizes, int n_in,
                              void* d_out, int out_size, void* d_ws, size_t ws_size,
                              hipStream_t stream)
{
    const float* x  = (const float*)d_in[0];
    const float* Wq = (const float*)d_in[2];
    const float* Wk = (const float*)d_in[3];
    const float* Wv = (const float*)d_in[4];
    const float* Wp = (const float*)d_in[5];
    const float* bp = (const float*)d_in[6];
    float* out = (float*)d_out;

    unsigned short* Q   = (unsigned short*)d_ws;
    unsigned short* K   = Q   + (size_t)TOKENS * D_MODEL;
    unsigned short* Vt  = K   + (size_t)TOKENS * D_MODEL;
    unsigned short* O   = Vt  + (size_t)TOKENS * D_MODEL;
    unsigned short* Wqb = O   + (size_t)TOKENS * D_MODEL;
    unsigned short* Wkb = Wqb + (size_t)D_MODEL * D_MODEL;
    unsigned short* Wvb = Wkb + (size_t)D_MODEL * D_MODEL;
    unsigned short* Wpb = Wvb + (size_t)D_MODEL * D_MODEL;

    convert_w<<<4096, 256, 0, stream>>>(Wq, Wk, Wv, Wp,
                                        Wqb, Wkb, Wvb, Wpb);
    qkv_gemm<<<dim3(TOKENS / 128, D_MODEL / 64), 512, 0, stream>>>(
        x, Wqb, Wkb, Wvb, Q, K, Vt);
    attn<<<dim3(BATCH * NUM_HEADS, SEQ / 128), 256, 0, stream>>>(Q, K, Vt, O);
    proj_gemm<<<dim3(TOKENS / 128, D_MODEL / 64), 512, 0, stream>>>(O, Wpb, bp, out);
}

// Round 14
// 168.116 us; speedup vs baseline: 1.1872x; 1.1872x over previous
//
#include <hip/hip_runtime.h>
#include <hip/hip_bf16.h>

#define D_MODEL 1024
#define NUM_HEADS 16
#define D_HEAD 64
#define BATCH 2
#define SEQ 2048
#define TOKENS (BATCH * SEQ) /* 4096 */

typedef __attribute__((ext_vector_type(8))) short bf16x8;
typedef __attribute__((ext_vector_type(4))) float f32x4;
typedef __attribute__((ext_vector_type(2))) unsigned int uint2v;

typedef __attribute__((address_space(1))) const unsigned int as1_uint;
typedef __attribute__((address_space(3))) unsigned int as3_uint;

#define LOG2E 1.44269504088896340736f

// round-to-nearest-even fp32 -> bf16 (bit pattern)
static __device__ __forceinline__ unsigned short f2bf(float f) {
    unsigned int u = __builtin_bit_cast(unsigned int, f);
    u += 0x7fffu + ((u >> 16) & 1u);
    return (unsigned short)(u >> 16);
}

// packed fp32x2 -> bf16x2 (lowers to v_cvt_pk_bf16_f32 on gfx950)
static __device__ __forceinline__ unsigned int pk2bf(float a, float b) {
    __hip_bfloat162 h = __float22bfloat162_rn(float2{a, b});
    unsigned int u;
    __builtin_memcpy(&u, &h, 4);
    return u;
}

// native v_exp_f32 (2^x)
static __device__ __forceinline__ float fast_exp2(float x) {
    return __builtin_amdgcn_exp2f(x);
}

// ---------------------------------------------------------------------------
// R25 (kept): weights-only fp32 -> bf16 conversion.
// ---------------------------------------------------------------------------
__global__ __launch_bounds__(256) void convert_w(
    const float* __restrict__ Wq, const float* __restrict__ Wk,
    const float* __restrict__ Wv, const float* __restrict__ Wp,
    unsigned short* __restrict__ Wqb, unsigned short* __restrict__ Wkb,
    unsigned short* __restrict__ Wvb, unsigned short* __restrict__ Wpb)
{
    int v = blockIdx.x * 256 + threadIdx.x;
    int w = v >> 18;
    int off = v & ((1 << 18) - 1);
    const float* s = (w == 0) ? Wq : (w == 1) ? Wk : (w == 2) ? Wv : Wp;
    unsigned short* d = (w == 0) ? Wqb : (w == 1) ? Wkb : (w == 2) ? Wvb : Wpb;
    float4 f = ((const float4*)s)[off];
    ushort4 o = { f2bf(f.x), f2bf(f.y), f2bf(f.z), f2bf(f.w) };
    ((ushort4*)d)[off] = o;
}

// ---------------------------------------------------------------------------
// R25 (kept): FUSED QKV projection reading x DIRECTLY as fp32. A-staging is
// T14 async-split: issue 2x float4 global loads at iter top, cvt + ds_write
// into buf^1 AFTER compute. Weights via async global_load_lds (preconverted).
// BN=64, 2 blocks/CU, dbuf one-sync.
// ---------------------------------------------------------------------------
__global__ __launch_bounds__(512, 4) void qkv_gemm(
    const float* __restrict__ x,
    const unsigned short* __restrict__ Wqb, const unsigned short* __restrict__ Wkb,
    const unsigned short* __restrict__ Wvb,
    unsigned short* __restrict__ Q, unsigned short* __restrict__ Kb,
    unsigned short* __restrict__ Vt)
{
    const int m0 = blockIdx.x * 128;
    const int n0 = blockIdx.y * 64;

    __shared__ __attribute__((aligned(16))) unsigned short sm[40960]; // 80 KB

    const int t = threadIdx.x;
    const int wave = t >> 6, lane = t & 63;
    const int wm = (wave & 1) * 64, wn = (wave >> 1) * 16;
    const int l15 = lane & 15, quad = lane >> 4;
    const int sw = l15 & 7;

    const unsigned short* Wz[3] = { Wqb, Wkb, Wvb };

    f32x4 acc[3][4];
#pragma unroll
    for (int z = 0; z < 3; z++)
#pragma unroll
        for (int i = 0; i < 4; i++) acc[z][i] = (f32x4)0.f;

    // weights: 512 16B chunks each (1/thread), async DMA
    auto stageW = [&](int k0, int buf) {
        int row = t >> 3, cp = t & 7;
        int c = cp ^ (row & 7);
        int fbase = wave * 64;
#pragma unroll
        for (int z = 0; z < 3; z++)
            __builtin_amdgcn_global_load_lds(
                (as1_uint*)&Wz[z][(size_t)(n0 + row) * D_MODEL + k0 + c * 8],
                (as3_uint*)&sm[buf * 20480 + 8192 + z * 4096 + fbase * 8],
                16, 0, 0);
    };

    // A: 1024 bf16-chunks (2/thread); fp32 source, same XOR-swizzled image
    float4 ar[2][2];
    auto loadA = [&](int k0) {
#pragma unroll
        for (int i = 0; i < 2; i++) {
            int f = wave * 64 + i * 512 + lane;
            int row = f >> 3, cp = f & 7;
            int c = cp ^ (row & 7);
            const float4* p = (const float4*)&x[(size_t)(m0 + row) * D_MODEL + k0 + c * 8];
            ar[i][0] = p[0];
            ar[i][1] = p[1];
        }
    };
    auto writeA = [&](int buf) {
#pragma unroll
        for (int i = 0; i < 2; i++) {
            int f = wave * 64 + i * 512 + lane;
            union { unsigned short s[8]; uint4 v; } u;
            u.s[0] = f2bf(ar[i][0].x); u.s[1] = f2bf(ar[i][0].y);
            u.s[2] = f2bf(ar[i][0].z); u.s[3] = f2bf(ar[i][0].w);
            u.s[4] = f2bf(ar[i][1].x); u.s[5] = f2bf(ar[i][1].y);
            u.s[6] = f2bf(ar[i][1].z); u.s[7] = f2bf(ar[i][1].w);
            *(uint4*)&sm[buf * 20480 + f * 8] = u.v;
        }
    };

    loadA(0);
    stageW(0, 0);
    writeA(0);
    __syncthreads();

    int cur = 0;
    for (int k0 = 0; k0 < D_MODEL; k0 += 64) {
        bool more = (k0 + 64 < D_MODEL);
        if (more) { stageW(k0 + 64, cur ^ 1); loadA(k0 + 64); }

        const unsigned short* lA = &sm[cur * 20480];
#pragma unroll
        for (int kk = 0; kk < 2; kk++) {
            const int cc = ((kk * 4 + quad) ^ sw) * 8;
            bf16x8 a[4];
#pragma unroll
            for (int mt = 0; mt < 4; mt++)
                a[mt] = *(const bf16x8*)&lA[(wm + mt * 16 + l15) * 64 + cc];
#pragma unroll
            for (int z = 0; z < 3; z++) {
                const unsigned short* lB = &sm[cur * 20480 + 8192 + z * 4096];
                bf16x8 b = *(const bf16x8*)&lB[(wn + l15) * 64 + cc];
#pragma unroll
                for (int mt = 0; mt < 4; mt++)
                    acc[z][mt] = __builtin_amdgcn_mfma_f32_16x16x32_bf16(
                        a[mt], b, acc[z][mt], 0, 0, 0);
            }
        }
        if (more) writeA(cur ^ 1);   // cvt + LDS write AFTER compute (T14)
        __syncthreads();             // drains W DMA + orders A writes
        cur ^= 1;
    }

    // ---- epilogue: Q (scaled by log2e), K, Vt ([b][h][dh][s])
#pragma unroll
    for (int mt = 0; mt < 4; mt++)
#pragma unroll
        for (int r = 0; r < 4; r++) {
            int row = m0 + wm + mt * 16 + quad * 4 + r;
            int col = n0 + wn + l15;
            Q[(size_t)row * D_MODEL + col]  = f2bf(acc[0][mt][r] * LOG2E);
            Kb[(size_t)row * D_MODEL + col] = f2bf(acc[1][mt][r]);
        }
    {
        const int b = m0 >> 11;
        const int srow = (m0 & 2047) + wm + quad * 4;
        const int h = n0 >> 6;
        const int dh = wn + l15;
#pragma unroll
        for (int mt = 0; mt < 4; mt++) {
            ushort4 pk = { f2bf(acc[2][mt][0]), f2bf(acc[2][mt][1]),
                           f2bf(acc[2][mt][2]), f2bf(acc[2][mt][3]) };
            *(ushort4*)&Vt[(size_t)((b * 16 + h) * 64 + dh) * SEQ + srow + mt * 16] = pk;
        }
    }
}

// ---------------------------------------------------------------------------
// Flash attention R26 (proven 47.4us): bh-major grid (XCD L2 locality,
// FETCH 69.7->12.3MB). Staging via global_load_lds (pre-swizzled source,
// linear LDS dest), dbuf, one barrier/iter, zero staging VGPRs. 64 KB LDS
// -> 2 blocks/CU, 16 waves/CU (the efficient frontier: R13 proved no-split
// is grid-starved, R7 proved KVBLK=128 spills, R11 proved setprio hurts).
// P in-register via cvt_pk + permlane{32,16}_swap (0 conflicts).
// 8 waves = 4 q-strips x 2 s-halves; 32 q/wave.
// ---------------------------------------------------------------------------
__global__ __launch_bounds__(512, 4) void attn(
    const unsigned short* __restrict__ Q, const unsigned short* __restrict__ K,
    const unsigned short* __restrict__ Vt, unsigned short* __restrict__ O)
{
    const int q0 = blockIdx.y * 128;
    const int bh = blockIdx.x;
    const int b = bh >> 4, h = bh & 15;
    const size_t base = (size_t)b * SEQ * D_MODEL + (size_t)h * D_HEAD;
    const size_t baseV = (size_t)bh * D_HEAD * SEQ;

    __shared__ __attribute__((aligned(16))) char smem[65536];
    unsigned short* lds = (unsigned short*)smem;

    const int t = threadIdx.x;
    const int wave = t >> 6, lane = t & 63;
    const int l15 = lane & 15, quad = lane >> 4;
    const int wq = wave & 3;
    const int sh = wave >> 2;
    const int qw = q0 + wq * 32;
    const int sbase = sh * (SEQ / 2);

    bf16x8 ones;
#pragma unroll
    for (int i = 0; i < 8; i++) ones[i] = (short)0x3F80;

    bf16x8 bq[2][2];
#pragma unroll
    for (int mq = 0; mq < 2; mq++)
#pragma unroll
        for (int kk = 0; kk < 2; kk++)
            bq[mq][kk] = *(const bf16x8*)&Q[base +
                (size_t)(qw + mq * 16 + l15) * D_MODEL + kk * 32 + quad * 8];

    const int tl = t & 255;
    const int sw = l15 & 7;

    // async staging: chunk f covers LDS bytes f*16 (linear dest); the XOR
    // swizzle is applied to the per-lane GLOBAL source column.
    auto stage = [&](int soff, int buf) {
#pragma unroll
        for (int i = 0; i < 2; i++) {
            int f = tl + i * 256;
            int row = f >> 3;
            int c = (f & 7) ^ (row & 7);
            __builtin_amdgcn_global_load_lds(
                (as1_uint*)&K[base + (size_t)(sbase + soff + row) * D_MODEL + c * 8],
                (as3_uint*)&lds[buf * 16384 + sh * 4096 + f * 8], 16, 0, 0);
            __builtin_amdgcn_global_load_lds(
                (as1_uint*)&Vt[baseV + (size_t)row * SEQ + sbase + soff + c * 8],
                (as3_uint*)&lds[8192 + buf * 16384 + sh * 4096 + f * 8], 16, 0, 0);
        }
    };

    f32x4 o_acc[2][4];
#pragma unroll
    for (int i = 0; i < 2; i++)
#pragma unroll
        for (int j = 0; j < 4; j++) o_acc[i][j] = (f32x4)0.f;
    f32x4 o_l[2];
#pragma unroll
    for (int i = 0; i < 2; i++) o_l[i] = (f32x4)0.f;

    stage(0, 0);
    __syncthreads();

    int cur = 0;
    for (int s0 = 0; s0 < SEQ / 2; s0 += 64) {
        if (s0 + 64 < SEQ / 2) stage(s0 + 64, cur ^ 1);

        const unsigned short* lK  = lds + cur * 16384 + sh * 4096;
        const unsigned short* lVt = lds + 8192 + cur * 16384 + sh * 4096;

        f32x4 st[4][2];
#pragma unroll
        for (int mt = 0; mt < 4; mt++)
#pragma unroll
            for (int mq = 0; mq < 2; mq++) st[mt][mq] = (f32x4)0.f;
#pragma unroll
        for (int kk = 0; kk < 2; kk++) {
            const int cc = ((kk * 4 + quad) ^ sw) * 8;
#pragma unroll
            for (int mt = 0; mt < 4; mt++) {
                bf16x8 ak = *(const bf16x8*)&lK[(mt * 16 + l15) * 64 + cc];
#pragma unroll
                for (int mq = 0; mq < 2; mq++)
                    st[mt][mq] = __builtin_amdgcn_mfma_f32_16x16x32_bf16(
                        ak, bq[mq][kk], st[mt][mq], 0, 0, 0);
            }
        }

#pragma unroll
        for (int mq = 0; mq < 2; mq++)
#pragma unroll
            for (int mt = 0; mt < 4; mt++)
#pragma unroll
                for (int r = 0; r < 4; r++)
                    st[mt][mq][r] = fast_exp2(st[mt][mq][r]);

        // P in-register: cvt_pk + permlane swaps -> PV A-fragments
        bf16x8 pa[2][2];
#pragma unroll
        for (int mq = 0; mq < 2; mq++)
#pragma unroll
            for (int kk = 0; kk < 2; kk++) {
                unsigned int cw[4];
#pragma unroll
                for (int j = 0; j < 2; j++) {
                    unsigned int w0 = pk2bf(st[2 * kk][mq][2 * j],
                                            st[2 * kk][mq][2 * j + 1]);
                    unsigned int w1 = pk2bf(st[2 * kk + 1][mq][2 * j],
                                            st[2 * kk + 1][mq][2 * j + 1]);
                    uint2v uv = __builtin_amdgcn_permlane32_swap(w0, w1, false, false);
                    uint2v f  = __builtin_amdgcn_permlane16_swap(uv[0], uv[1], false, false);
                    cw[j]     = f[0];
                    cw[2 + j] = f[1];
                }
                union { unsigned int w[4]; bf16x8 v; } uu;
                uu.w[0] = cw[0]; uu.w[1] = cw[1]; uu.w[2] = cw[2]; uu.w[3] = cw[3];
                pa[mq][kk] = uu.v;
            }

#pragma unroll
        for (int kk = 0; kk < 2; kk++) {
            const int cc = ((kk * 4 + quad) ^ sw) * 8;
            bf16x8 bv[4];
#pragma unroll
            for (int nt = 0; nt < 4; nt++)
                bv[nt] = *(const bf16x8*)&lVt[(nt * 16 + l15) * 64 + cc];
#pragma unroll
            for (int mq = 0; mq < 2; mq++) {
#pragma unroll
                for (int nt = 0; nt < 4; nt++)
                    o_acc[mq][nt] = __builtin_amdgcn_mfma_f32_16x16x32_bf16(
                        pa[mq][kk], bv[nt], o_acc[mq][nt], 0, 0, 0);
                o_l[mq] = __builtin_amdgcn_mfma_f32_16x16x32_bf16(
                    pa[mq][kk], ones, o_l[mq], 0, 0, 0);
            }
        }
        __syncthreads();   // drains vmcnt: next tile landed; cur free
        cur ^= 1;
    }

    float* sO = (float*)&smem[0];
    float* sL = (float*)&smem[36864];
    if (sh == 1) {
#pragma unroll
        for (int mq = 0; mq < 2; mq++) {
#pragma unroll
            for (int r = 0; r < 4; r++)
                sL[wq * 32 + mq * 16 + quad * 4 + r] = o_l[mq][r];
#pragma unroll
            for (int nt = 0; nt < 4; nt++)
#pragma unroll
                for (int r = 0; r < 4; r++)
                    sO[(wq * 32 + mq * 16 + quad * 4 + r) * 68 + nt * 16 + l15] =
                        o_acc[mq][nt][r];
        }
    }
    __syncthreads();
    if (sh == 0) {
#pragma unroll
        for (int mq = 0; mq < 2; mq++) {
            float inv[4];
#pragma unroll
            for (int r = 0; r < 4; r++)
                inv[r] = 1.f / (o_l[mq][r] + sL[wq * 32 + mq * 16 + quad * 4 + r]);
#pragma unroll
            for (int nt = 0; nt < 4; nt++)
#pragma unroll
                for (int r = 0; r < 4; r++) {
                    int row = qw + mq * 16 + quad * 4 + r;
                    float v = o_acc[mq][nt][r] +
                              sO[(wq * 32 + mq * 16 + quad * 4 + r) * 68 + nt * 16 + l15];
                    O[base + (size_t)row * D_MODEL + nt * 16 + l15] = f2bf(v * inv[r]);
                }
        }
    }
}

// ---------------------------------------------------------------------------
// R21 (proven): Output projection, BN=64 + dbuf one-sync, 2 blocks/CU.
// ---------------------------------------------------------------------------
__global__ __launch_bounds__(512, 4) void proj_gemm(
    const unsigned short* __restrict__ A, const unsigned short* __restrict__ W,
    const float* __restrict__ bias, float* __restrict__ out)
{
    const int m0 = blockIdx.x * 128;
    const int n0 = blockIdx.y * 64;

    __shared__ __attribute__((aligned(16))) unsigned short sm[24576]; // 48 KB

    const int t = threadIdx.x;
    const int wave = t >> 6, lane = t & 63;
    const int wm = (wave & 1) * 64, wn = (wave >> 1) * 16;
    const int l15 = lane & 15, quad = lane >> 4;
    const int sw = l15 & 7;

    f32x4 acc[4];
#pragma unroll
    for (int i = 0; i < 4; i++) acc[i] = (f32x4)0.f;

    auto stage = [&](int k0, int buf) {
#pragma unroll
        for (int i = 0; i < 2; i++) {
            int fbase = wave * 64 + i * 512;
            int f = fbase + lane;
            int row = f >> 3, cp = f & 7;
            int c = cp ^ (row & 7);
            __builtin_amdgcn_global_load_lds(
                (as1_uint*)&A[(size_t)(m0 + row) * D_MODEL + k0 + c * 8],
                (as3_uint*)&sm[buf * 12288 + fbase * 8], 16, 0, 0);
        }
        {
            int row = t >> 3, cp = t & 7;
            int c = cp ^ (row & 7);
            int fbase = wave * 64;
            __builtin_amdgcn_global_load_lds(
                (as1_uint*)&W[(size_t)(n0 + row) * D_MODEL + k0 + c * 8],
                (as3_uint*)&sm[buf * 12288 + 8192 + fbase * 8], 16, 0, 0);
        }
    };

    stage(0, 0);
    __syncthreads();

    int cur = 0;
    for (int k0 = 0; k0 < D_MODEL; k0 += 64) {
        if (k0 + 64 < D_MODEL) stage(k0 + 64, cur ^ 1);

        const unsigned short* lA = &sm[cur * 12288];
        const unsigned short* lB = &sm[cur * 12288 + 8192];
#pragma unroll
        for (int kk = 0; kk < 2; kk++) {
            const int cc = ((kk * 4 + quad) ^ sw) * 8;
            bf16x8 a[4];
#pragma unroll
            for (int mt = 0; mt < 4; mt++)
                a[mt] = *(const bf16x8*)&lA[(wm + mt * 16 + l15) * 64 + cc];
            bf16x8 b = *(const bf16x8*)&lB[(wn + l15) * 64 + cc];
#pragma unroll
            for (int mt = 0; mt < 4; mt++)
                acc[mt] = __builtin_amdgcn_mfma_f32_16x16x32_bf16(
                    a[mt], b, acc[mt], 0, 0, 0);
        }
        __syncthreads();
        cur ^= 1;
    }

    const int col = n0 + wn + l15;
    const float bc = bias[col];
#pragma unroll
    for (int mt = 0; mt < 4; mt++)
#pragma unroll
        for (int r = 0; r < 4; r++) {
            int row = m0 + wm + mt * 16 + quad * 4 + r;
            out[(size_t)row * D_MODEL + col] = acc[mt][r] + bc;
        }
}

extern "C" void kernel_launch(void* const* d_in, const int* in_sizes, int n_in,
                              void* d_out, int out_size, void* d_ws, size_t ws_size,
                              hipStream_t stream)
{
    const float* x  = (const float*)d_in[0];
    const float* Wq = (const float*)d_in[2];
    const float* Wk = (const float*)d_in[3];
    const float* Wv = (const float*)d_in[4];
    const float* Wp = (const float*)d_in[5];
    const float* bp = (const float*)d_in[6];
    float* out = (float*)d_out;

    unsigned short* Q   = (unsigned short*)d_ws;
    unsigned short* K   = Q   + (size_t)TOKENS * D_MODEL;
    unsigned short* Vt  = K   + (size_t)TOKENS * D_MODEL;
    unsigned short* O   = Vt  + (size_t)TOKENS * D_MODEL;
    unsigned short* Wqb = O   + (size_t)TOKENS * D_MODEL;
    unsigned short* Wkb = Wqb + (size_t)D_MODEL * D_MODEL;
    unsigned short* Wvb = Wkb + (size_t)D_MODEL * D_MODEL;
    unsigned short* Wpb = Wvb + (size_t)D_MODEL * D_MODEL;

    convert_w<<<4096, 256, 0, stream>>>(Wq, Wk, Wv, Wp,
                                        Wqb, Wkb, Wvb, Wpb);
    qkv_gemm<<<dim3(TOKENS / 128, D_MODEL / 64), 512, 0, stream>>>(
        x, Wqb, Wkb, Wvb, Q, K, Vt);
    attn<<<dim3(BATCH * NUM_HEADS, SEQ / 128), 512, 0, stream>>>(Q, K, Vt, O);
    proj_gemm<<<dim3(TOKENS / 128, D_MODEL / 64), 512, 0, stream>>>(O, Wpb, bp, out);
}